// Round 1
// baseline (16314.003 us; speedup 1.0000x reference)
//
#include <hip/hip_runtime.h>

// GIN regression: pre-MLP -> 3x(GINConv) with BN after first two -> mean-pool -> head MLP.
// H = 10 hidden features. fp32 throughout.

static constexpr int HF = 10;   // hidden features
static constexpr int FIN = 16;  // input features

// ---------------- pre_mp: h = x @ preW + preb ----------------
__global__ void pre_mp_kernel(const float* __restrict__ x, const float* __restrict__ W,
                              const float* __restrict__ b, float* __restrict__ h, int N) {
    int i = blockIdx.x * blockDim.x + threadIdx.x;
    if (i >= N) return;
    float xv[FIN];
    const float* xr = x + (size_t)i * FIN;
#pragma unroll
    for (int k = 0; k < FIN; ++k) xv[k] = xr[k];
    float acc[HF];
#pragma unroll
    for (int j = 0; j < HF; ++j) acc[j] = b[j];
#pragma unroll
    for (int k = 0; k < FIN; ++k) {
#pragma unroll
        for (int j = 0; j < HF; ++j) acc[j] = fmaf(xv[k], W[k * HF + j], acc[j]);
    }
    float* hr = h + (size_t)i * HF;
#pragma unroll
    for (int j = 0; j < HF; ++j) hr[j] = acc[j];
}

// ---------------- edge scatter: agg[dst] += BN(h[src]) ----------------
// BN (if enabled) is a per-channel affine (scale, shift) folded from the previous
// layer's batchnorm, applied at read time (saves a full normalize pass).
template <bool BN>
__global__ void scatter_kernel(const int* __restrict__ src, const int* __restrict__ dst,
                               const float* __restrict__ h, const float* __restrict__ ss,
                               float* agg, int E) {
    int e = blockIdx.x * blockDim.x + threadIdx.x;
    if (e >= E) return;
    int s = src[e];
    int d = dst[e];
    const float* hr = h + (size_t)s * HF;
    float* ar = agg + (size_t)d * HF;
#pragma unroll
    for (int j = 0; j < HF; ++j) {
        float v = hr[j];
        if (BN) v = fmaf(v, ss[j], ss[HF + j]);
        unsafeAtomicAdd(&ar[j], v);
    }
}

// ---------------- node update: out = MLP(BN(h) + agg); optional BN-stat accumulation.
// NOTE: out may alias agg (row-wise in-place) -> no __restrict__ on those.
template <bool BN, bool STATS>
__global__ void update_kernel(const float* __restrict__ h, const float* agg,
                              const float* __restrict__ ss,
                              const float* __restrict__ W1, const float* __restrict__ b1,
                              const float* __restrict__ W2, const float* __restrict__ b2,
                              float* out, int N, float* stats) {
    int i = blockIdx.x * blockDim.x + threadIdx.x;
    float o[HF];
    bool act = (i < N);
    if (act) {
        float z[HF];
        const float* hr = h + (size_t)i * HF;
        const float* ar = agg + (size_t)i * HF;
#pragma unroll
        for (int j = 0; j < HF; ++j) {
            float v = hr[j];
            if (BN) v = fmaf(v, ss[j], ss[HF + j]);
            z[j] = v + ar[j];
        }
        float t[HF];
#pragma unroll
        for (int j = 0; j < HF; ++j) {
            float a = b1[j];
#pragma unroll
            for (int k = 0; k < HF; ++k) a = fmaf(z[k], W1[k * HF + j], a);
            t[j] = fmaxf(a, 0.0f);
        }
        float* orow = out + (size_t)i * HF;
#pragma unroll
        for (int j = 0; j < HF; ++j) {
            float a = b2[j];
#pragma unroll
            for (int k = 0; k < HF; ++k) a = fmaf(t[k], W2[k * HF + j], a);
            o[j] = a;
            orow[j] = a;
        }
    } else {
#pragma unroll
        for (int j = 0; j < HF; ++j) o[j] = 0.0f;
    }
    if (STATS) {
        // wave(64)-level reduction of per-channel sum and sum-of-squares
#pragma unroll
        for (int j = 0; j < HF; ++j) {
            float s = o[j];
            float q = o[j] * o[j];
#pragma unroll
            for (int off = 32; off > 0; off >>= 1) {
                s += __shfl_down(s, off);
                q += __shfl_down(q, off);
            }
            if ((threadIdx.x & 63) == 0) {
                unsafeAtomicAdd(&stats[j], s);
                unsafeAtomicAdd(&stats[HF + j], q);
            }
        }
    }
}

// ---------------- finalize BN: stats -> (scale, shift) ----------------
__global__ void bn_finalize_kernel(const float* __restrict__ stats,
                                   const float* __restrict__ gamma,
                                   const float* __restrict__ beta,
                                   float* __restrict__ ss, float invN) {
    int j = threadIdx.x;
    if (j >= HF) return;
    float mean = stats[j] * invN;
    float var = stats[HF + j] * invN - mean * mean;
    float sc = gamma[j] * rsqrtf(var + 1e-5f);
    ss[j] = sc;
    ss[HF + j] = beta[j] - mean * sc;
}

// ---------------- pooling: segment sums + counts ----------------
__global__ void pool_kernel(const float* __restrict__ h, const int* __restrict__ batch,
                            float* pool, float* cnt, int N) {
    int i = blockIdx.x * blockDim.x + threadIdx.x;
    if (i >= N) return;
    int g = batch[i];
    const float* hr = h + (size_t)i * HF;
    float* pr = pool + (size_t)g * HF;
#pragma unroll
    for (int j = 0; j < HF; ++j) unsafeAtomicAdd(&pr[j], hr[j]);
    unsafeAtomicAdd(&cnt[g], 1.0f);
}

// ---------------- head: out = relu(mean @ W1 + b1) @ W2 + b2 ----------------
__global__ void head_kernel(const float* __restrict__ pool, const float* __restrict__ cnt,
                            const float* __restrict__ W1, const float* __restrict__ b1,
                            const float* __restrict__ W2, const float* __restrict__ b2,
                            float* __restrict__ out, int G) {
    int g = blockIdx.x * blockDim.x + threadIdx.x;
    if (g >= G) return;
    float inv = 1.0f / fmaxf(cnt[g], 1.0f);
    float p[HF];
    const float* pr = pool + (size_t)g * HF;
#pragma unroll
    for (int j = 0; j < HF; ++j) p[j] = pr[j] * inv;
    float acc = b2[0];
#pragma unroll
    for (int j = 0; j < HF; ++j) {
        float a = b1[j];
#pragma unroll
        for (int k = 0; k < HF; ++k) a = fmaf(p[k], W1[k * HF + j], a);
        acc = fmaf(fmaxf(a, 0.0f), W2[j], acc);
    }
    out[g] = acc;
}

extern "C" void kernel_launch(void* const* d_in, const int* in_sizes, int n_in,
                              void* d_out, int out_size, void* d_ws, size_t ws_size,
                              hipStream_t stream) {
    const float* x      = (const float*)d_in[0];
    const int*   ei     = (const int*)d_in[1];
    const int*   batch  = (const int*)d_in[2];
    const float* preW   = (const float*)d_in[3];
    const float* preb   = (const float*)d_in[4];
    const float* convW1 = (const float*)d_in[5];
    const float* convb1 = (const float*)d_in[6];
    const float* convW2 = (const float*)d_in[7];
    const float* convb2 = (const float*)d_in[8];
    const float* gamma  = (const float*)d_in[9];
    const float* beta   = (const float*)d_in[10];
    const float* postW1 = (const float*)d_in[11];
    const float* postb1 = (const float*)d_in[12];
    const float* postW2 = (const float*)d_in[13];
    const float* postb2 = (const float*)d_in[14];

    const int N = in_sizes[0] / FIN;
    const int E = in_sizes[1] / 2;
    const int G = out_size;

    const int* src = ei;
    const int* dst = ei + E;

    // workspace layout: two ping-pong node buffers + small area
    size_t nh = (size_t)N * HF * sizeof(float);
    char* base = (char*)d_ws;
    float* buf0 = (float*)base;
    float* buf1 = (float*)(base + nh);
    float* small = (float*)(base + 2 * nh);
    float* stats = small;        // 20 floats (sum, sumsq)
    float* ss0   = small + 32;   // 20 floats (scale, shift) for BN layer 0
    float* ss1   = small + 64;   // 20 floats for BN layer 1
    float* pool  = small + 96;            // G*HF floats
    float* cnt   = pool + (size_t)G * HF; // G floats

    const int BLK = 256;
    int gN = (N + BLK - 1) / BLK;
    int gE = (E + BLK - 1) / BLK;
    int gG = (G + BLK - 1) / BLK;
    float invN = 1.0f / (float)N;

    // ---- pre_mp -> buf0
    pre_mp_kernel<<<gN, BLK, 0, stream>>>(x, preW, preb, buf0, N);

    // ---- layer 0: conv(buf0) -> buf1 (in-place over agg), stats
    hipMemsetAsync(buf1, 0, nh, stream);
    hipMemsetAsync(stats, 0, 2 * HF * sizeof(float), stream);
    scatter_kernel<false><<<gE, BLK, 0, stream>>>(src, dst, buf0, nullptr, buf1, E);
    update_kernel<false, true><<<gN, BLK, 0, stream>>>(buf0, buf1, nullptr,
        convW1 + 0 * HF * HF, convb1 + 0 * HF, convW2 + 0 * HF * HF, convb2 + 0 * HF,
        buf1, N, stats);
    bn_finalize_kernel<<<1, 64, 0, stream>>>(stats, gamma + 0 * HF, beta + 0 * HF, ss0, invN);

    // ---- layer 1: conv(BN0(buf1)) -> buf0, stats
    hipMemsetAsync(buf0, 0, nh, stream);
    hipMemsetAsync(stats, 0, 2 * HF * sizeof(float), stream);
    scatter_kernel<true><<<gE, BLK, 0, stream>>>(src, dst, buf1, ss0, buf0, E);
    update_kernel<true, true><<<gN, BLK, 0, stream>>>(buf1, buf0, ss0,
        convW1 + 1 * HF * HF, convb1 + 1 * HF, convW2 + 1 * HF * HF, convb2 + 1 * HF,
        buf0, N, stats);
    bn_finalize_kernel<<<1, 64, 0, stream>>>(stats, gamma + 1 * HF, beta + 1 * HF, ss1, invN);

    // ---- layer 2: conv(BN1(buf0)) -> buf1, no stats
    hipMemsetAsync(buf1, 0, nh, stream);
    scatter_kernel<true><<<gE, BLK, 0, stream>>>(src, dst, buf0, ss1, buf1, E);
    update_kernel<true, false><<<gN, BLK, 0, stream>>>(buf0, buf1, ss1,
        convW1 + 2 * HF * HF, convb1 + 2 * HF, convW2 + 2 * HF * HF, convb2 + 2 * HF,
        buf1, N, nullptr);

    // ---- pooling + head
    hipMemsetAsync(pool, 0, (size_t)G * (HF + 1) * sizeof(float), stream);
    pool_kernel<<<gN, BLK, 0, stream>>>(buf1, batch, pool, cnt, N);
    head_kernel<<<gG, BLK, 0, stream>>>(pool, cnt, postW1, postb1, postW2, postb2,
                                        (float*)d_out, G);
}

// Round 2
// 4755.185 us; speedup vs baseline: 3.4308x; 3.4308x over previous
//
#include <hip/hip_runtime.h>

// GIN regression: pre-MLP -> 3x GINConv (BN folded as read-time affine) -> mean-pool -> head.
// Fast path: build dst-CSR once per call (16M atomics), then pure-gather fused conv layers.
// Fallback path (ws too small): round-1 scatter/update (proven correct).

static constexpr int HF = 10;   // hidden features
static constexpr int HP = 12;   // padded row stride (48 B -> float4-aligned rows)
static constexpr int FIN = 16;  // input features
static constexpr int BLK = 256;

static inline size_t alignup(size_t x) { return (x + 255) & ~(size_t)255; }

// ---------------- pre_mp: h = x @ preW + preb ----------------
template <int STRIDE>
__global__ void pre_mp_kernel(const float* __restrict__ x, const float* __restrict__ W,
                              const float* __restrict__ b, float* __restrict__ h, int N) {
    int i = blockIdx.x * blockDim.x + threadIdx.x;
    if (i >= N) return;
    const float4* xr = (const float4*)(x + (size_t)i * FIN);  // 64B-aligned rows
    float xv[FIN];
    float4 x0 = xr[0], x1 = xr[1], x2 = xr[2], x3 = xr[3];
    xv[0]=x0.x; xv[1]=x0.y; xv[2]=x0.z; xv[3]=x0.w;
    xv[4]=x1.x; xv[5]=x1.y; xv[6]=x1.z; xv[7]=x1.w;
    xv[8]=x2.x; xv[9]=x2.y; xv[10]=x2.z; xv[11]=x2.w;
    xv[12]=x3.x; xv[13]=x3.y; xv[14]=x3.z; xv[15]=x3.w;
    float acc[HF];
#pragma unroll
    for (int j = 0; j < HF; ++j) acc[j] = b[j];
#pragma unroll
    for (int k = 0; k < FIN; ++k) {
#pragma unroll
        for (int j = 0; j < HF; ++j) acc[j] = fmaf(xv[k], W[k * HF + j], acc[j]);
    }
    float* hr = h + (size_t)i * STRIDE;
    if constexpr (STRIDE == HP) {
        ((float4*)hr)[0] = make_float4(acc[0], acc[1], acc[2], acc[3]);
        ((float4*)hr)[1] = make_float4(acc[4], acc[5], acc[6], acc[7]);
        ((float4*)hr)[2] = make_float4(acc[8], acc[9], 0.0f, 0.0f);
    } else {
#pragma unroll
        for (int j = 0; j < HF; ++j) hr[j] = acc[j];
    }
}

// ---------------- CSR construction ----------------
__global__ void hist_kernel(const int* __restrict__ dst, int* __restrict__ deg, int E) {
    int e = blockIdx.x * blockDim.x + threadIdx.x;
    if (e >= E) return;
    atomicAdd(&deg[dst[e]], 1);
}

__global__ void blocksum_kernel(const int* __restrict__ deg, int* __restrict__ bsum, int N) {
    int i = blockIdx.x * BLK + threadIdx.x;
    int v = (i < N) ? deg[i] : 0;
#pragma unroll
    for (int off = 32; off > 0; off >>= 1) v += __shfl_down(v, off);
    __shared__ int sm[BLK / 64];
    if ((threadIdx.x & 63) == 0) sm[threadIdx.x >> 6] = v;
    __syncthreads();
    if (threadIdx.x == 0) {
        int t = 0;
#pragma unroll
        for (int w = 0; w < BLK / 64; ++w) t += sm[w];
        bsum[blockIdx.x] = t;
    }
}

// exclusive scan of block sums, single block of 1024 threads
__global__ void scan_bsum_kernel(int* __restrict__ bs, int nb) {
    __shared__ int sm[1024];
    int running = 0;
    for (int base = 0; base < nb; base += 1024) {
        int i = base + (int)threadIdx.x;
        int v = (i < nb) ? bs[i] : 0;
        sm[threadIdx.x] = v;
        __syncthreads();
        for (int off = 1; off < 1024; off <<= 1) {
            int t = (threadIdx.x >= (unsigned)off) ? sm[threadIdx.x - off] : 0;
            __syncthreads();
            sm[threadIdx.x] += t;
            __syncthreads();
        }
        int incl = sm[threadIdx.x];
        if (i < nb) bs[i] = running + incl - v;  // exclusive
        int chunk_total = sm[1023];
        __syncthreads();
        running += chunk_total;
    }
}

__global__ void rowptr_kernel(const int* __restrict__ deg, const int* __restrict__ bsum,
                              int* __restrict__ rowptr, int* __restrict__ cursor, int N) {
    int i = blockIdx.x * BLK + threadIdx.x;
    int v = (i < N) ? deg[i] : 0;
    __shared__ int sm[BLK];
    sm[threadIdx.x] = v;
    __syncthreads();
    for (int off = 1; off < BLK; off <<= 1) {
        int t = (threadIdx.x >= (unsigned)off) ? sm[threadIdx.x - off] : 0;
        __syncthreads();
        sm[threadIdx.x] += t;
        __syncthreads();
    }
    int excl = sm[threadIdx.x] - v + bsum[blockIdx.x];
    if (i < N) {
        rowptr[i] = excl;
        cursor[i] = excl;
    }
}

__global__ void fill_kernel(const int* __restrict__ src, const int* __restrict__ dst,
                            int* __restrict__ cursor, int* __restrict__ csr, int E) {
    int e = blockIdx.x * blockDim.x + threadIdx.x;
    if (e >= E) return;
    int pos = atomicAdd(&cursor[dst[e]], 1);
    csr[pos] = src[e];
}

// ---------------- fused conv: z = BN(h_i) + sum_j BN(h_j); out = MLP(z) ----------------
// BN folded: BN(h) = sc*h + sh  =>  z = sc*(h_i + sum h_j) + (deg+1)*sh
template <bool BN, bool STATS, bool POOL>
__global__ void conv_kernel(const float* __restrict__ hin,
                            const int* __restrict__ rowptr, const int* __restrict__ deg,
                            const int* __restrict__ csr, const float* __restrict__ ss,
                            const float* __restrict__ W1, const float* __restrict__ b1,
                            const float* __restrict__ W2, const float* __restrict__ b2,
                            float* __restrict__ hout, int N, float* stats,
                            const int* __restrict__ batch, float* pool, float* cnt) {
    int i = blockIdx.x * blockDim.x + threadIdx.x;
    bool act = i < N;
    float o[HF];
    int g = 0x7fffffff;
    if (act) {
        const float4* hp = (const float4*)(hin + (size_t)i * HP);
        float4 r0 = hp[0], r1 = hp[1], r2 = hp[2];
        float z[HF] = {r0.x, r0.y, r0.z, r0.w, r1.x, r1.y, r1.z, r1.w, r2.x, r2.y};
        int base = rowptr[i];
        int d = deg[i];
        for (int k = 0; k < d; ++k) {
            int s = csr[base + k];
            const float4* sp = (const float4*)(hin + (size_t)s * HP);
            float4 a0 = sp[0], a1 = sp[1], a2 = sp[2];
            z[0] += a0.x; z[1] += a0.y; z[2] += a0.z; z[3] += a0.w;
            z[4] += a1.x; z[5] += a1.y; z[6] += a1.z; z[7] += a1.w;
            z[8] += a2.x; z[9] += a2.y;
        }
        if (BN) {
            float dp1 = (float)(d + 1);
#pragma unroll
            for (int j = 0; j < HF; ++j) z[j] = fmaf(z[j], ss[j], dp1 * ss[HF + j]);
        }
        float t[HF];
#pragma unroll
        for (int j = 0; j < HF; ++j) {
            float a = b1[j];
#pragma unroll
            for (int k = 0; k < HF; ++k) a = fmaf(z[k], W1[k * HF + j], a);
            t[j] = fmaxf(a, 0.0f);
        }
#pragma unroll
        for (int j = 0; j < HF; ++j) {
            float a = b2[j];
#pragma unroll
            for (int k = 0; k < HF; ++k) a = fmaf(t[k], W2[k * HF + j], a);
            o[j] = a;
        }
        if (!POOL) {
            float* orow = hout + (size_t)i * HP;
            ((float4*)orow)[0] = make_float4(o[0], o[1], o[2], o[3]);
            ((float4*)orow)[1] = make_float4(o[4], o[5], o[6], o[7]);
            ((float4*)orow)[2] = make_float4(o[8], o[9], 0.0f, 0.0f);
        } else {
            g = batch[i];
        }
    } else {
#pragma unroll
        for (int j = 0; j < HF; ++j) o[j] = 0.0f;
    }
    if (STATS) {
#pragma unroll
        for (int j = 0; j < HF; ++j) {
            float s = o[j];
            float q = o[j] * o[j];
#pragma unroll
            for (int off = 32; off > 0; off >>= 1) {
                s += __shfl_down(s, off);
                q += __shfl_down(q, off);
            }
            if ((threadIdx.x & 63) == 0) {
                unsafeAtomicAdd(&stats[j], s);
                unsafeAtomicAdd(&stats[HF + j], q);
            }
        }
    }
    if (POOL) {
        // wave-level segmented sum (batch is sorted): few atomics per wave
        int lane = threadIdx.x & 63;
        float c1 = act ? 1.0f : 0.0f;
#pragma unroll
        for (int off = 1; off < 64; off <<= 1) {
            int gu = __shfl_up(g, off);
            float cu = __shfl_up(c1, off);
            bool take = (lane >= off) && (gu == g);
            if (take) c1 += cu;
#pragma unroll
            for (int j = 0; j < HF; ++j) {
                float vu = __shfl_up(o[j], off);
                if (take) o[j] += vu;
            }
        }
        int gn = __shfl_down(g, 1);
        bool last = (lane == 63) || (gn != g);
        if (act && last) {
#pragma unroll
            for (int j = 0; j < HF; ++j) unsafeAtomicAdd(&pool[(size_t)g * HF + j], o[j]);
            unsafeAtomicAdd(&cnt[g], c1);
        }
    }
}

// ---------------- finalize BN: stats -> (scale, shift) ----------------
__global__ void bn_finalize_kernel(const float* __restrict__ stats,
                                   const float* __restrict__ gamma,
                                   const float* __restrict__ beta,
                                   float* __restrict__ ss, float invN) {
    int j = threadIdx.x;
    if (j >= HF) return;
    float mean = stats[j] * invN;
    float var = stats[HF + j] * invN - mean * mean;
    float sc = gamma[j] * rsqrtf(var + 1e-5f);
    ss[j] = sc;
    ss[HF + j] = beta[j] - mean * sc;
}

// ---------------- head: out = relu(mean @ W1 + b1) @ W2 + b2 ----------------
__global__ void head_kernel(const float* __restrict__ pool, const float* __restrict__ cnt,
                            const float* __restrict__ W1, const float* __restrict__ b1,
                            const float* __restrict__ W2, const float* __restrict__ b2,
                            float* __restrict__ out, int G) {
    int g = blockIdx.x * blockDim.x + threadIdx.x;
    if (g >= G) return;
    float inv = 1.0f / fmaxf(cnt[g], 1.0f);
    float p[HF];
    const float* pr = pool + (size_t)g * HF;
#pragma unroll
    for (int j = 0; j < HF; ++j) p[j] = pr[j] * inv;
    float acc = b2[0];
#pragma unroll
    for (int j = 0; j < HF; ++j) {
        float a = b1[j];
#pragma unroll
        for (int k = 0; k < HF; ++k) a = fmaf(p[k], W1[k * HF + j], a);
        acc = fmaf(fmaxf(a, 0.0f), W2[j], acc);
    }
    out[g] = acc;
}

// ================= fallback (round-1 proven) kernels =================
template <bool BN>
__global__ void scatter_kernel(const int* __restrict__ src, const int* __restrict__ dst,
                               const float* __restrict__ h, const float* __restrict__ ss,
                               float* agg, int E) {
    int e = blockIdx.x * blockDim.x + threadIdx.x;
    if (e >= E) return;
    int s = src[e];
    int d = dst[e];
    const float* hr = h + (size_t)s * HF;
    float* ar = agg + (size_t)d * HF;
#pragma unroll
    for (int j = 0; j < HF; ++j) {
        float v = hr[j];
        if (BN) v = fmaf(v, ss[j], ss[HF + j]);
        unsafeAtomicAdd(&ar[j], v);
    }
}

template <bool BN, bool STATS>
__global__ void update_kernel(const float* __restrict__ h, const float* agg,
                              const float* __restrict__ ss,
                              const float* __restrict__ W1, const float* __restrict__ b1,
                              const float* __restrict__ W2, const float* __restrict__ b2,
                              float* out, int N, float* stats) {
    int i = blockIdx.x * blockDim.x + threadIdx.x;
    float o[HF];
    bool act = (i < N);
    if (act) {
        float z[HF];
        const float* hr = h + (size_t)i * HF;
        const float* ar = agg + (size_t)i * HF;
#pragma unroll
        for (int j = 0; j < HF; ++j) {
            float v = hr[j];
            if (BN) v = fmaf(v, ss[j], ss[HF + j]);
            z[j] = v + ar[j];
        }
        float t[HF];
#pragma unroll
        for (int j = 0; j < HF; ++j) {
            float a = b1[j];
#pragma unroll
            for (int k = 0; k < HF; ++k) a = fmaf(z[k], W1[k * HF + j], a);
            t[j] = fmaxf(a, 0.0f);
        }
        float* orow = out + (size_t)i * HF;
#pragma unroll
        for (int j = 0; j < HF; ++j) {
            float a = b2[j];
#pragma unroll
            for (int k = 0; k < HF; ++k) a = fmaf(t[k], W2[k * HF + j], a);
            o[j] = a;
            orow[j] = a;
        }
    } else {
#pragma unroll
        for (int j = 0; j < HF; ++j) o[j] = 0.0f;
    }
    if (STATS) {
#pragma unroll
        for (int j = 0; j < HF; ++j) {
            float s = o[j];
            float q = o[j] * o[j];
#pragma unroll
            for (int off = 32; off > 0; off >>= 1) {
                s += __shfl_down(s, off);
                q += __shfl_down(q, off);
            }
            if ((threadIdx.x & 63) == 0) {
                unsafeAtomicAdd(&stats[j], s);
                unsafeAtomicAdd(&stats[HF + j], q);
            }
        }
    }
}

__global__ void pool_atomic_kernel(const float* __restrict__ h, const int* __restrict__ batch,
                                   float* pool, float* cnt, int N) {
    int i = blockIdx.x * blockDim.x + threadIdx.x;
    if (i >= N) return;
    int g = batch[i];
    const float* hr = h + (size_t)i * HF;
    float* pr = pool + (size_t)g * HF;
#pragma unroll
    for (int j = 0; j < HF; ++j) unsafeAtomicAdd(&pr[j], hr[j]);
    unsafeAtomicAdd(&cnt[g], 1.0f);
}

extern "C" void kernel_launch(void* const* d_in, const int* in_sizes, int n_in,
                              void* d_out, int out_size, void* d_ws, size_t ws_size,
                              hipStream_t stream) {
    const float* x      = (const float*)d_in[0];
    const int*   ei     = (const int*)d_in[1];
    const int*   batch  = (const int*)d_in[2];
    const float* preW   = (const float*)d_in[3];
    const float* preb   = (const float*)d_in[4];
    const float* convW1 = (const float*)d_in[5];
    const float* convb1 = (const float*)d_in[6];
    const float* convW2 = (const float*)d_in[7];
    const float* convb2 = (const float*)d_in[8];
    const float* gamma  = (const float*)d_in[9];
    const float* beta   = (const float*)d_in[10];
    const float* postW1 = (const float*)d_in[11];
    const float* postb1 = (const float*)d_in[12];
    const float* postW2 = (const float*)d_in[13];
    const float* postb2 = (const float*)d_in[14];

    const int N = in_sizes[0] / FIN;
    const int E = in_sizes[1] / 2;
    const int G = out_size;
    const int* src = ei;
    const int* dst = ei + E;

    const int gN = (N + BLK - 1) / BLK;
    const int gE = (E + BLK - 1) / BLK;
    const int gG = (G + BLK - 1) / BLK;
    const int nblk = gN;
    const float invN = 1.0f / (float)N;

    // fast-path workspace layout
    size_t off = 0;
    auto take = [&](size_t bytes) { size_t o = off; off += alignup(bytes); return o; };
    size_t csr_o = take((size_t)E * 4);
    size_t h0_o  = take((size_t)N * HP * 4);
    size_t h1_o  = take((size_t)N * HP * 4);
    size_t deg_o = take((size_t)N * 4);
    size_t row_o = take((size_t)N * 4);
    size_t cur_o = take((size_t)N * 4);
    size_t bs_o  = take((size_t)nblk * 4);
    size_t sm_o  = take(4096 + (size_t)G * (HF + 1) * 4);
    char* base = (char*)d_ws;

    if (off <= ws_size) {
        // =================== fast path ===================
        int*   csr    = (int*)(base + csr_o);
        float* h0     = (float*)(base + h0_o);
        float* h1     = (float*)(base + h1_o);
        int*   deg    = (int*)(base + deg_o);
        int*   rowptr = (int*)(base + row_o);
        int*   cursor = (int*)(base + cur_o);
        int*   bsum   = (int*)(base + bs_o);
        float* small  = (float*)(base + sm_o);
        float* stats0 = small;        // 20
        float* stats1 = small + 32;   // 20
        float* ss0    = small + 64;   // 20
        float* ss1    = small + 96;   // 20
        float* pool   = small + 128;  // G*HF
        float* cnt    = pool + (size_t)G * HF;  // G

        // pre_mp and CSR build are independent
        pre_mp_kernel<HP><<<gN, BLK, 0, stream>>>(x, preW, preb, h0, N);

        hipMemsetAsync(deg, 0, (size_t)N * 4, stream);
        hipMemsetAsync(stats0, 0, 64 * 4, stream);                       // stats0+stats1
        hipMemsetAsync(pool, 0, (size_t)G * (HF + 1) * 4, stream);       // pool+cnt
        hist_kernel<<<gE, BLK, 0, stream>>>(dst, deg, E);
        blocksum_kernel<<<nblk, BLK, 0, stream>>>(deg, bsum, N);
        scan_bsum_kernel<<<1, 1024, 0, stream>>>(bsum, nblk);
        rowptr_kernel<<<nblk, BLK, 0, stream>>>(deg, bsum, rowptr, cursor, N);
        fill_kernel<<<gE, BLK, 0, stream>>>(src, dst, cursor, csr, E);

        // layer 0: h0 -> h1, stats0
        conv_kernel<false, true, false><<<gN, BLK, 0, stream>>>(h0, rowptr, deg, csr, nullptr,
            convW1 + 0 * HF * HF, convb1 + 0 * HF, convW2 + 0 * HF * HF, convb2 + 0 * HF,
            h1, N, stats0, nullptr, nullptr, nullptr);
        bn_finalize_kernel<<<1, 64, 0, stream>>>(stats0, gamma + 0 * HF, beta + 0 * HF, ss0, invN);

        // layer 1: h1 -> h0, stats1
        conv_kernel<true, true, false><<<gN, BLK, 0, stream>>>(h1, rowptr, deg, csr, ss0,
            convW1 + 1 * HF * HF, convb1 + 1 * HF, convW2 + 1 * HF * HF, convb2 + 1 * HF,
            h0, N, stats1, nullptr, nullptr, nullptr);
        bn_finalize_kernel<<<1, 64, 0, stream>>>(stats1, gamma + 1 * HF, beta + 1 * HF, ss1, invN);

        // layer 2: h0 -> pooled directly (segmented-scan atomics)
        conv_kernel<true, false, true><<<gN, BLK, 0, stream>>>(h0, rowptr, deg, csr, ss1,
            convW1 + 2 * HF * HF, convb1 + 2 * HF, convW2 + 2 * HF * HF, convb2 + 2 * HF,
            nullptr, N, nullptr, batch, pool, cnt);

        head_kernel<<<gG, BLK, 0, stream>>>(pool, cnt, postW1, postb1, postW2, postb2,
                                            (float*)d_out, G);
    } else {
        // =================== fallback path (round-1) ===================
        size_t nh = (size_t)N * HF * sizeof(float);
        float* buf0 = (float*)base;
        float* buf1 = (float*)(base + nh);
        float* small = (float*)(base + 2 * nh);
        float* stats = small;
        float* ss0   = small + 32;
        float* ss1   = small + 64;
        float* pool  = small + 96;
        float* cnt   = pool + (size_t)G * HF;

        pre_mp_kernel<HF><<<gN, BLK, 0, stream>>>(x, preW, preb, buf0, N);

        hipMemsetAsync(buf1, 0, nh, stream);
        hipMemsetAsync(stats, 0, 2 * HF * sizeof(float), stream);
        scatter_kernel<false><<<gE, BLK, 0, stream>>>(src, dst, buf0, nullptr, buf1, E);
        update_kernel<false, true><<<gN, BLK, 0, stream>>>(buf0, buf1, nullptr,
            convW1 + 0 * HF * HF, convb1 + 0 * HF, convW2 + 0 * HF * HF, convb2 + 0 * HF,
            buf1, N, stats);
        bn_finalize_kernel<<<1, 64, 0, stream>>>(stats, gamma + 0 * HF, beta + 0 * HF, ss0, invN);

        hipMemsetAsync(buf0, 0, nh, stream);
        hipMemsetAsync(stats, 0, 2 * HF * sizeof(float), stream);
        scatter_kernel<true><<<gE, BLK, 0, stream>>>(src, dst, buf1, ss0, buf0, E);
        update_kernel<true, true><<<gN, BLK, 0, stream>>>(buf1, buf0, ss0,
            convW1 + 1 * HF * HF, convb1 + 1 * HF, convW2 + 1 * HF * HF, convb2 + 1 * HF,
            buf0, N, stats);
        bn_finalize_kernel<<<1, 64, 0, stream>>>(stats, gamma + 1 * HF, beta + 1 * HF, ss1, invN);

        hipMemsetAsync(buf1, 0, nh, stream);
        scatter_kernel<true><<<gE, BLK, 0, stream>>>(src, dst, buf0, ss1, buf1, E);
        update_kernel<true, false><<<gN, BLK, 0, stream>>>(buf0, buf1, ss1,
            convW1 + 2 * HF * HF, convb1 + 2 * HF, convW2 + 2 * HF * HF, convb2 + 2 * HF,
            buf1, N, nullptr);

        hipMemsetAsync(pool, 0, (size_t)G * (HF + 1) * sizeof(float), stream);
        pool_atomic_kernel<<<gN, BLK, 0, stream>>>(buf1, batch, pool, cnt, N);
        head_kernel<<<gG, BLK, 0, stream>>>(pool, cnt, postW1, postb1, postW2, postb2,
                                            (float*)d_out, G);
    }
}